// Round 13
// baseline (709.523 us; speedup 1.0000x reference)
//
#include <hip/hip_runtime.h>
#include <hip/hip_fp16.h>
#include <math.h>

// PBELoss: power-flow residual loss.
// residual_i = Sbus_i - V_i * conj( sum_{e: dst(e)=i} Y_e * V_{src(e)} )
// out = [ mean|res|, mean|Re res|, mean|Im res| ]
//
// Fast path: prep+hist (merged) -> prefix -> bin (8192-edge tiles, LDS-staged
// bucket sort, 1 LDS atomic/edge, coalesced NT copy-out) -> bucket accumulate
// (exact int32 fixed-point, fused residual reduce) -> finalize.
// Fallback (small ws): per-edge packed 64-bit fixed-point atomicAdd.

#define PBE_NT     256
#define PBE_NB     512          // buckets
#define PBE_BSHIFT 12           // 4096 nodes/bucket
#define PBE_BSIZE  4096
#define PBE_TILE   8192
#define PBE_NTB    512          // threads in bin kernel
#define PBE_EPT    16           // consecutive edges per thread

#define PBE_SCALE64       2097152.0f      // 2^21 (fallback)
#define PBE_INV_SCALE64   (1.0f / 2097152.0f)
#define PBE_SCALE_LDS     524288.0f       // 2^19 (bucket accumulate)
#define PBE_INV_SCALE_LDS (1.0f / 524288.0f)

typedef unsigned long long ull;
typedef int   iv4 __attribute__((ext_vector_type(4)));
typedef float fv4 __attribute__((ext_vector_type(4)));
union H2U { __half2 h; unsigned u; };

__device__ __forceinline__ float2 ld_nt_f2(const float2* p) {
    double d = __builtin_nontemporal_load(reinterpret_cast<const double*>(p));
    union { double d; float2 f; } u; u.d = d;
    return u.f;
}
__device__ __forceinline__ int ld_nt_i(const int* p) {
    return __builtin_nontemporal_load(p);
}
__device__ __forceinline__ int2 ld_nt_i2(const int* p) {
    long long v = __builtin_nontemporal_load(reinterpret_cast<const long long*>(p));
    int2 r; r.x = (int)(unsigned)(v & 0xFFFFFFFFll); r.y = (int)(v >> 32);
    return r;
}
__device__ __forceinline__ iv4 ld_nt_iv4(const int* p) {
    return __builtin_nontemporal_load(reinterpret_cast<const iv4*>(p));
}
__device__ __forceinline__ fv4 ld_nt_fv4(const float* p) {
    return __builtin_nontemporal_load(reinterpret_cast<const fv4*>(p));
}

// ---------------- merged node prep + dst histogram ---------------------------
__global__ void pbe_prep_hist(const float* __restrict__ pred,
                              const float* __restrict__ target,
                              const int* __restrict__ mask,
                              float* __restrict__ V,
                              float* __restrict__ S,
                              unsigned* __restrict__ Vh,
                              int n,
                              const int* __restrict__ dst,
                              unsigned* __restrict__ hist_g,
                              int e_total) {
    __shared__ unsigned h[PBE_NB];
    for (int b = threadIdx.x; b < PBE_NB; b += blockDim.x) h[b] = 0;
    __syncthreads();
    int gtid = blockIdx.x * blockDim.x + threadIdx.x;
    int stride = gridDim.x * blockDim.x;
    for (int i = gtid; i < n; i += stride) {
        int b = 6 * i;
        float2 p0 = ld_nt_f2((const float2*)(pred + b));
        float2 p1 = ld_nt_f2((const float2*)(pred + b + 2));
        float2 p2 = ld_nt_f2((const float2*)(pred + b + 4));
        float2 t0 = ld_nt_f2((const float2*)(target + b));
        float2 t1 = ld_nt_f2((const float2*)(target + b + 2));
        float2 t2 = ld_nt_f2((const float2*)(target + b + 4));
        int2 m0 = ld_nt_i2(mask + b);
        int2 m1 = ld_nt_i2(mask + b + 2);
        int2 m2 = ld_nt_i2(mask + b + 4);
        float pd = m0.x ? p0.x : t0.x;
        float qd = m0.y ? p0.y : t0.y;
        float pg = m1.x ? p1.x : t1.x;
        float qg = m1.y ? p1.y : t1.y;
        float vm = m2.x ? p2.x : t2.x;
        float va = m2.y ? p2.y : t2.y;
        float sn, cs;
        sincosf(va, &sn, &cs);
        float vr = vm * cs, vi = vm * sn;
        V[2 * i + 0] = vr;
        V[2 * i + 1] = vi;
        S[2 * i + 0] = pg - pd;
        S[2 * i + 1] = qg - qd;
        H2U u; u.h = __floats2half2_rn(vr, vi); Vh[i] = u.u;
    }
    int n4 = e_total >> 2;
    for (int i = gtid; i < n4; i += stride) {
        iv4 v = ld_nt_iv4(dst + 4 * i);
        atomicAdd(&h[((unsigned)v[0]) >> PBE_BSHIFT], 1u);
        atomicAdd(&h[((unsigned)v[1]) >> PBE_BSHIFT], 1u);
        atomicAdd(&h[((unsigned)v[2]) >> PBE_BSHIFT], 1u);
        atomicAdd(&h[((unsigned)v[3]) >> PBE_BSHIFT], 1u);
    }
    if (blockIdx.x == 0) {
        for (int t = (n4 << 2) + threadIdx.x; t < e_total; t += blockDim.x)
            atomicAdd(&h[((unsigned)dst[t]) >> PBE_BSHIFT], 1u);
    }
    __syncthreads();
    for (int b = threadIdx.x; b < PBE_NB; b += blockDim.x)
        if (h[b]) atomicAdd(&hist_g[b], h[b]);
}

// ---------------- prefix -> base, cursor -------------------------------------
__global__ void pbe_prefix(const unsigned* __restrict__ hist_g,
                           unsigned* __restrict__ base,
                           unsigned* __restrict__ cursor) {
    __shared__ unsigned tmp[PBE_NB];
    int t = threadIdx.x;
    unsigned mine = hist_g[t];
    tmp[t] = mine;
    __syncthreads();
    for (int o = 1; o < PBE_NB; o <<= 1) {
        unsigned u = (t >= o) ? tmp[t - o] : 0u;
        __syncthreads();
        tmp[t] += u;
        __syncthreads();
    }
    unsigned excl = tmp[t] - mine;
    base[t] = excl;
    cursor[t] = excl;
}

// ---------------- bin: 8192-edge tiles, 1 LDS atomic per edge ----------------
// LDS: hist 2K + lbase 2K + wsum 32 + staged 4 + recs 64K ~= 68.2 KB
// -> 2 blocks/CU (occupancy proven non-binding in r8).
__global__ void __launch_bounds__(PBE_NTB)
pbe_bin(const float* __restrict__ Y,          // [E] float2 interleaved
        const int* __restrict__ src,
        const int* __restrict__ dst,
        const unsigned* __restrict__ Vh,
        ull* __restrict__ rec,
        unsigned* __restrict__ cursor,
        int e_total) {
    __shared__ unsigned hist[PBE_NB];     // phase1: counts; phase2+: delta
    __shared__ unsigned lbase[PBE_NB];    // phase2+: exclusive prefix (const)
    __shared__ unsigned wsum[8];
    __shared__ unsigned staged_sh;
    __shared__ ull recs[PBE_TILE];        // 64 KB (bkt in bits 44+)

    const int tile0 = blockIdx.x * PBE_TILE;
    const int tid = threadIdx.x;
    hist[tid] = 0;                        // PBE_NTB == PBE_NB == 512
    __syncthreads();

    const int ebase = tile0 + tid * PBE_EPT;
    const bool full = (tile0 + PBE_TILE) <= e_total;

    // phase 1: dst loads (4x int4) + fused histogram/rank
    int d[PBE_EPT];
    unsigned short r[PBE_EPT];
    if (full) {
        #pragma unroll
        for (int m = 0; m < PBE_EPT / 4; ++m) {
            iv4 a = ld_nt_iv4(dst + ebase + 4 * m);
            d[4*m+0]=a[0]; d[4*m+1]=a[1]; d[4*m+2]=a[2]; d[4*m+3]=a[3];
        }
    } else {
        #pragma unroll
        for (int j = 0; j < PBE_EPT; ++j)
            d[j] = (ebase + j < e_total) ? dst[ebase + j] : -1;
    }
    #pragma unroll
    for (int k = 0; k < PBE_EPT; ++k) {
        r[k] = 0;
        if (d[k] >= 0)
            r[k] = (unsigned short)atomicAdd(&hist[((unsigned)d[k]) >> PBE_BSHIFT], 1u);
    }
    __syncthreads();

    // phase 2: shfl wave-scan + cross-wave scan + exact global reservation.
    {
        unsigned mine = hist[tid];
        unsigned v = mine;
        #pragma unroll
        for (int o = 1; o < 64; o <<= 1) {
            unsigned u = __shfl_up(v, o);
            if ((tid & 63) >= o) v += u;
        }
        if ((tid & 63) == 63) wsum[tid >> 6] = v;
        __syncthreads();
        if (tid == 0) {
            unsigned acc = 0;
            #pragma unroll
            for (int wv = 0; wv < 8; ++wv) {
                unsigned t = wsum[wv]; wsum[wv] = acc; acc += t;
            }
        }
        __syncthreads();
        unsigned incl = v + wsum[tid >> 6];
        unsigned excl = incl - mine;
        lbase[tid] = excl;
        if (tid == PBE_NB - 1) staged_sh = incl;
        unsigned g = mine ? atomicAdd(&cursor[tid], mine) : 0u;
        hist[tid] = g - excl;             // delta; per-thread slot, no hazard
    }
    __syncthreads();

    // phase 3: two batches of 8 edges (cap VGPR): src 2x int4 + Y 4x float4
    // + gathers -> LDS scatter at lbase[b] + rank (no atomic).
    #pragma unroll
    for (int hblk = 0; hblk < PBE_EPT / 8; ++hblk) {
        const int kb = hblk * 8;
        const int eb = ebase + kb;
        int s[8]; float2 y[8]; unsigned uv[8];
        if (full) {
            iv4 a = ld_nt_iv4(src + eb);
            iv4 b = ld_nt_iv4(src + eb + 4);
            s[0]=a[0]; s[1]=a[1]; s[2]=a[2]; s[3]=a[3];
            s[4]=b[0]; s[5]=b[1]; s[6]=b[2]; s[7]=b[3];
            #pragma unroll
            for (int m = 0; m < 4; ++m) {
                fv4 q = ld_nt_fv4(Y + 2 * (eb + 2 * m));
                y[2*m+0] = make_float2(q[0], q[1]);
                y[2*m+1] = make_float2(q[2], q[3]);
            }
        } else {
            #pragma unroll
            for (int j = 0; j < 8; ++j) {
                s[j] = (d[kb + j] >= 0) ? src[eb + j] : 0;
                y[j] = (d[kb + j] >= 0) ? *(const float2*)(Y + 2 * (eb + j))
                                        : make_float2(0.f, 0.f);
            }
        }
        #pragma unroll
        for (int j = 0; j < 8; ++j) uv[j] = Vh[s[j]];  // random gathers
        #pragma unroll
        for (int j = 0; j < 8; ++j) {
            int k = kb + j;
            if (d[k] < 0) continue;
            unsigned b = ((unsigned)d[k]) >> PBE_BSHIFT;
            unsigned pos = lbase[b] + r[k];
            H2U uvh; uvh.u = uv[j];
            float vr = __low2float(uvh.h), vi = __high2float(uvh.h);
            float mr = y[j].x * vr - y[j].y * vi;
            float mi = y[j].x * vi + y[j].y * vr;
            H2U um; um.h = __floats2half2_rn(mr, mi);
            recs[pos] = ((ull)b << 44)
                      | ((ull)(unsigned)(d[k] & (PBE_BSIZE - 1)) << 32)
                      | um.u;
        }
    }
    __syncthreads();

    // phase 4: coalesced copy-out; strip bucket bits. NT stores keep rec
    // lines out of L2.
    unsigned staged = staged_sh;
    for (unsigned j = tid; j < staged; j += PBE_NTB) {
        ull rr = recs[j];
        unsigned b = (unsigned)(rr >> 44);
        __builtin_nontemporal_store(rr & 0xFFFFFFFFFFFull, &rec[j + hist[b]]);
    }
}

// ---------------- per-bucket accumulate + fused residual reduce --------------
#define PBE_NTA 1024
__global__ void __launch_bounds__(PBE_NTA)
pbe_bucket_acc_red(const ull* __restrict__ rec,
                   const unsigned* __restrict__ base,
                   const unsigned* __restrict__ cursor, // post-bin end
                   const float* __restrict__ V,
                   const float* __restrict__ S,
                   float* __restrict__ sums, int n_nodes) {
    __shared__ int accR[PBE_BSIZE];
    __shared__ int accI[PBE_BSIZE];
    for (int j = threadIdx.x; j < PBE_BSIZE; j += PBE_NTA) { accR[j] = 0; accI[j] = 0; }
    __syncthreads();
    const int b = blockIdx.x;
    const unsigned lo = base[b], hi = cursor[b];
    for (unsigned t = lo + threadIdx.x; t < hi; t += PBE_NTA) {
        ull p = __builtin_nontemporal_load(rec + t);
        H2U um; um.u = (unsigned)p;
        unsigned dl = (unsigned)(p >> 32) & (PBE_BSIZE - 1);
        atomicAdd(&accR[dl], __float2int_rn(__low2float(um.h) * PBE_SCALE_LDS));
        atomicAdd(&accI[dl], __float2int_rn(__high2float(um.h) * PBE_SCALE_LDS));
    }
    __syncthreads();
    const int node0 = b << PBE_BSHIFT;
    float a0 = 0.f, a1 = 0.f, a2 = 0.f;
    for (int j = threadIdx.x; j < PBE_BSIZE; j += PBE_NTA) {
        int n = node0 + j;
        if (n < n_nodes) {
            float2 v  = reinterpret_cast<const float2*>(V)[n];
            float2 sb = reinterpret_cast<const float2*>(S)[n];
            float cr = accR[j] * PBE_INV_SCALE_LDS;
            float ci = accI[j] * PBE_INV_SCALE_LDS;
            float rr = sb.x - (v.x * cr + v.y * ci);
            float ri = sb.y - (v.y * cr - v.x * ci);
            a0 += sqrtf(rr * rr + ri * ri);
            a1 += fabsf(rr);
            a2 += fabsf(ri);
        }
    }
    #pragma unroll
    for (int off = 32; off > 0; off >>= 1) {
        a0 += __shfl_down(a0, off);
        a1 += __shfl_down(a1, off);
        a2 += __shfl_down(a2, off);
    }
    __shared__ float sm[3][PBE_NTA / 64];
    int wid  = threadIdx.x >> 6;
    int lane = threadIdx.x & 63;
    if (lane == 0) { sm[0][wid] = a0; sm[1][wid] = a1; sm[2][wid] = a2; }
    __syncthreads();
    if (threadIdx.x == 0) {
        float t0 = 0.f, t1 = 0.f, t2 = 0.f;
        #pragma unroll
        for (int wv = 0; wv < PBE_NTA / 64; ++wv) {
            t0 += sm[0][wv]; t1 += sm[1][wv]; t2 += sm[2][wv];
        }
        atomicAdd(&sums[0], t0);
        atomicAdd(&sums[1], t1);
        atomicAdd(&sums[2], t2);
    }
}

// ---------------- fallback path ----------------------------------------------
__global__ void pbe_node_prep(const float* __restrict__ pred,
                              const float* __restrict__ target,
                              const int* __restrict__ mask,
                              float* __restrict__ V,
                              float* __restrict__ S,
                              int n) {
    int i = blockIdx.x * blockDim.x + threadIdx.x;
    int stride = gridDim.x * blockDim.x;
    for (; i < n; i += stride) {
        int b = 6 * i;
        float2 p0 = ld_nt_f2((const float2*)(pred + b));
        float2 p1 = ld_nt_f2((const float2*)(pred + b + 2));
        float2 p2 = ld_nt_f2((const float2*)(pred + b + 4));
        float2 t0 = ld_nt_f2((const float2*)(target + b));
        float2 t1 = ld_nt_f2((const float2*)(target + b + 2));
        float2 t2 = ld_nt_f2((const float2*)(target + b + 4));
        int2 m0 = ld_nt_i2(mask + b);
        int2 m1 = ld_nt_i2(mask + b + 2);
        int2 m2 = ld_nt_i2(mask + b + 4);
        float pd = m0.x ? p0.x : t0.x;
        float qd = m0.y ? p0.y : t0.y;
        float pg = m1.x ? p1.x : t1.x;
        float qg = m1.y ? p1.y : t1.y;
        float vm = m2.x ? p2.x : t2.x;
        float va = m2.y ? p2.y : t2.y;
        float sn, cs;
        sincosf(va, &sn, &cs);
        V[2 * i + 0] = vm * cs;
        V[2 * i + 1] = vm * sn;
        S[2 * i + 0] = pg - pd;
        S[2 * i + 1] = qg - qd;
    }
}

__device__ __forceinline__ void pbe_edge_one(float2 gb, int s, int d,
                                             const float2* __restrict__ V,
                                             ull* __restrict__ Iq) {
    float2 v = V[s];
    float mr = gb.x * v.x - gb.y * v.y;
    float mi = gb.x * v.y + gb.y * v.x;
    int qr = __float2int_rn(mr * PBE_SCALE64);
    int qi = __float2int_rn(mi * PBE_SCALE64);
    ull pack = ((ull)(unsigned)qr << 32) + (ull)(long long)qi;
    atomicAdd(&Iq[d], pack);
}

__global__ void __launch_bounds__(PBE_NT)
pbe_edge_scatter(const float2* __restrict__ edge_attr,
                 const int* __restrict__ src,
                 const int* __restrict__ dst,
                 const float2* __restrict__ V,
                 ull* __restrict__ Iq,
                 int e_total) {
    int i = blockIdx.x * blockDim.x + threadIdx.x;
    const int stride = gridDim.x * blockDim.x;
    for (; i < e_total; i += stride) {
        float2 g = ld_nt_f2(edge_attr + i);
        pbe_edge_one(g, ld_nt_i(src + i), ld_nt_i(dst + i), V, Iq);
    }
}

__global__ void pbe_unpack_iq(ull* __restrict__ Iq, float* __restrict__ I, int n) {
    int i = blockIdx.x * blockDim.x + threadIdx.x;
    int stride = gridDim.x * blockDim.x;
    for (; i < n; i += stride) {
        long long q = (long long)Iq[i];
        int lo = (int)(unsigned)(q & 0xFFFFFFFFll);
        int hi = (int)((q - (long long)lo) >> 32);
        I[2 * i + 0] = hi * PBE_INV_SCALE64;
        I[2 * i + 1] = lo * PBE_INV_SCALE64;
    }
}

__global__ void pbe_reduce(const float* __restrict__ V,
                           const float* __restrict__ S,
                           const float* __restrict__ I,
                           float* __restrict__ sums, int n) {
    float a0 = 0.f, a1 = 0.f, a2 = 0.f;
    int i = blockIdx.x * blockDim.x + threadIdx.x;
    int stride = gridDim.x * blockDim.x;
    for (; i < n; i += stride) {
        float2 v  = reinterpret_cast<const float2*>(V)[i];
        float2 sb = reinterpret_cast<const float2*>(S)[i];
        float2 cc = reinterpret_cast<const float2*>(I)[i];
        float rr = sb.x - (v.x * cc.x + v.y * cc.y);
        float ri = sb.y - (v.y * cc.x - v.x * cc.y);
        a0 += sqrtf(rr * rr + ri * ri);
        a1 += fabsf(rr);
        a2 += fabsf(ri);
    }
    #pragma unroll
    for (int off = 32; off > 0; off >>= 1) {
        a0 += __shfl_down(a0, off);
        a1 += __shfl_down(a1, off);
        a2 += __shfl_down(a2, off);
    }
    __shared__ float sm[3][PBE_NT / 64];
    int wid  = threadIdx.x >> 6;
    int lane = threadIdx.x & 63;
    if (lane == 0) { sm[0][wid] = a0; sm[1][wid] = a1; sm[2][wid] = a2; }
    __syncthreads();
    if (threadIdx.x == 0) {
        float t0 = 0.f, t1 = 0.f, t2 = 0.f;
        #pragma unroll
        for (int w = 0; w < PBE_NT / 64; ++w) {
            t0 += sm[0][w]; t1 += sm[1][w]; t2 += sm[2][w];
        }
        atomicAdd(&sums[0], t0);
        atomicAdd(&sums[1], t1);
        atomicAdd(&sums[2], t2);
    }
}

__global__ void pbe_finalize(const float* __restrict__ sums,
                             float* __restrict__ out, float inv_n) {
    int t = threadIdx.x;
    if (t < 3) out[t] = sums[t] * inv_n;
}

static inline size_t align256(size_t x) { return (x + 255) & ~(size_t)255; }

extern "C" void kernel_launch(void* const* d_in, const int* in_sizes, int n_in,
                              void* d_out, int out_size, void* d_ws, size_t ws_size,
                              hipStream_t stream) {
    const float* pred      = (const float*)d_in[0];
    const float* target    = (const float*)d_in[1];
    const float* edge_attr = (const float*)d_in[2];
    const int*   edge_idx  = (const int*)d_in[3]; // [2, E] int32
    const int*   mask      = (const int*)d_in[4]; // bool -> int32

    const int n_nodes = in_sizes[0] / 6;
    const int n_edges = in_sizes[2] / 2;
    const int* src = edge_idx;
    const int* dst = edge_idx + n_edges;

    const int NBa     = (n_nodes + PBE_BSIZE - 1) / PBE_BSIZE;  // active buckets
    const int n_tiles = (n_edges + PBE_TILE - 1) / PBE_TILE;

    char* w = (char*)d_ws;
    size_t oV    = 0;
    size_t oS    = align256(oV + (size_t)2 * n_nodes * 4);
    size_t oVh   = align256(oS + (size_t)2 * n_nodes * 4);
    size_t oRec  = align256(oVh + (size_t)n_nodes * 4);
    size_t oHist = align256(oRec + (size_t)n_edges * 8);   // exact capacity
    size_t oBase = align256(oHist + PBE_NB * 4);
    size_t oCur  = align256(oBase + PBE_NB * 4);
    size_t oSums = align256(oCur + PBE_NB * 4);
    size_t need  = oSums + 3 * 4;

    float*    V      = (float*)(w + oV);
    float*    S      = (float*)(w + oS);
    unsigned* Vh     = (unsigned*)(w + oVh);
    ull*      rec    = (ull*)(w + oRec);
    unsigned* hist_g = (unsigned*)(w + oHist);
    unsigned* base   = (unsigned*)(w + oBase);
    unsigned* cursor = (unsigned*)(w + oCur);
    float*    sums   = (float*)(w + oSums);

    const bool fast = (ws_size >= need) && (NBa <= PBE_NB);

    const int T = PBE_NT;
    int grid_nodes = (n_nodes + T - 1) / T;
    if (grid_nodes > 2048) grid_nodes = 2048;

    if (fast) {
        hipMemsetAsync(hist_g, 0, PBE_NB * sizeof(unsigned), stream);
        hipMemsetAsync(sums, 0, 3 * sizeof(float), stream);

        pbe_prep_hist<<<2048, T, 0, stream>>>(pred, target, mask, V, S, Vh,
                                              n_nodes, dst, hist_g, n_edges);
        pbe_prefix<<<1, PBE_NB, 0, stream>>>(hist_g, base, cursor);
        pbe_bin<<<n_tiles, PBE_NTB, 0, stream>>>(edge_attr, src, dst, Vh,
                                                 rec, cursor, n_edges);
        pbe_bucket_acc_red<<<NBa, PBE_NTA, 0, stream>>>(rec, base, cursor, V, S,
                                                        sums, n_nodes);
        pbe_finalize<<<1, 64, 0, stream>>>(sums, (float*)d_out, 1.0f / (float)n_nodes);
    } else {
        // fallback: packed 64-bit fixed-point atomics (round-3 scheme)
        ull* Iq = (ull*)(w + oRec);
        float* sums_fb = (float*)(w + oVh);
        hipMemsetAsync(Iq, 0, (size_t)n_nodes * 8, stream);
        hipMemsetAsync(sums_fb, 0, 3 * sizeof(float), stream);
        int grid_edges = (n_edges + T - 1) / T;
        if (grid_edges > 8192) grid_edges = 8192;
        pbe_node_prep<<<grid_nodes, T, 0, stream>>>(pred, target, mask, V, S, n_nodes);
        pbe_edge_scatter<<<grid_edges, T, 0, stream>>>(
            (const float2*)edge_attr, src, dst, (const float2*)V, Iq, n_edges);
        pbe_unpack_iq<<<grid_nodes, T, 0, stream>>>(Iq, (float*)Iq, n_nodes);
        pbe_reduce<<<grid_nodes, T, 0, stream>>>(V, S, (float*)Iq, sums_fb, n_nodes);
        pbe_finalize<<<1, 64, 0, stream>>>(sums_fb, (float*)d_out, 1.0f / (float)n_nodes);
    }
}

// Round 16
// 642.442 us; speedup vs baseline: 1.1044x; 1.1044x over previous
//
#include <hip/hip_runtime.h>
#include <hip/hip_fp16.h>
#include <math.h>

// PBELoss: power-flow residual loss.
// residual_i = Sbus_i - V_i * conj( sum_{e: dst(e)=i} Y_e * V_{src(e)} )
// out = [ mean|res|, mean|Re res|, mean|Im res| ]
//
// Best-known configuration (consolidated from rounds 8/11/12 A/B evidence):
//   prep+hist (merged) -> prefix -> bin (4096-edge tiles, LDS-staged bucket
//   sort, 1 LDS atomic/edge, SCALAR NT stream loads, coalesced NT copy-out)
//   -> bucket accumulate (exact int32 fixed-point, fused residual reduce,
//   1024 threads) -> finalize.
// Fallback (small ws): per-edge packed 64-bit fixed-point atomicAdd.

#define PBE_NT     256
#define PBE_NB     512          // buckets
#define PBE_BSHIFT 12           // 4096 nodes/bucket
#define PBE_BSIZE  4096
#define PBE_TILE   4096
#define PBE_NTB    512          // threads in bin kernel
#define PBE_EPT    8            // edges per thread (strided within tile)

#define PBE_SCALE64       2097152.0f      // 2^21 (fallback)
#define PBE_INV_SCALE64   (1.0f / 2097152.0f)
#define PBE_SCALE_LDS     524288.0f       // 2^19 (bucket accumulate)
#define PBE_INV_SCALE_LDS (1.0f / 524288.0f)

typedef unsigned long long ull;
typedef int   iv4 __attribute__((ext_vector_type(4)));
union H2U { __half2 h; unsigned u; };

__device__ __forceinline__ float2 ld_nt_f2(const float2* p) {
    double d = __builtin_nontemporal_load(reinterpret_cast<const double*>(p));
    union { double d; float2 f; } u; u.d = d;
    return u.f;
}
__device__ __forceinline__ int ld_nt_i(const int* p) {
    return __builtin_nontemporal_load(p);
}
__device__ __forceinline__ int2 ld_nt_i2(const int* p) {
    long long v = __builtin_nontemporal_load(reinterpret_cast<const long long*>(p));
    int2 r; r.x = (int)(unsigned)(v & 0xFFFFFFFFll); r.y = (int)(v >> 32);
    return r;
}
__device__ __forceinline__ iv4 ld_nt_iv4(const int* p) {
    return __builtin_nontemporal_load(reinterpret_cast<const iv4*>(p));
}

// ---------------- merged node prep + dst histogram ---------------------------
__global__ void pbe_prep_hist(const float* __restrict__ pred,
                              const float* __restrict__ target,
                              const int* __restrict__ mask,
                              float* __restrict__ V,
                              float* __restrict__ S,
                              unsigned* __restrict__ Vh,
                              int n,
                              const int* __restrict__ dst,
                              unsigned* __restrict__ hist_g,
                              int e_total) {
    __shared__ unsigned h[PBE_NB];
    for (int b = threadIdx.x; b < PBE_NB; b += blockDim.x) h[b] = 0;
    __syncthreads();
    int gtid = blockIdx.x * blockDim.x + threadIdx.x;
    int stride = gridDim.x * blockDim.x;
    for (int i = gtid; i < n; i += stride) {
        int b = 6 * i;
        float2 p0 = ld_nt_f2((const float2*)(pred + b));
        float2 p1 = ld_nt_f2((const float2*)(pred + b + 2));
        float2 p2 = ld_nt_f2((const float2*)(pred + b + 4));
        float2 t0 = ld_nt_f2((const float2*)(target + b));
        float2 t1 = ld_nt_f2((const float2*)(target + b + 2));
        float2 t2 = ld_nt_f2((const float2*)(target + b + 4));
        int2 m0 = ld_nt_i2(mask + b);
        int2 m1 = ld_nt_i2(mask + b + 2);
        int2 m2 = ld_nt_i2(mask + b + 4);
        float pd = m0.x ? p0.x : t0.x;
        float qd = m0.y ? p0.y : t0.y;
        float pg = m1.x ? p1.x : t1.x;
        float qg = m1.y ? p1.y : t1.y;
        float vm = m2.x ? p2.x : t2.x;
        float va = m2.y ? p2.y : t2.y;
        float sn, cs;
        sincosf(va, &sn, &cs);
        float vr = vm * cs, vi = vm * sn;
        V[2 * i + 0] = vr;
        V[2 * i + 1] = vi;
        S[2 * i + 0] = pg - pd;
        S[2 * i + 1] = qg - qd;
        H2U u; u.h = __floats2half2_rn(vr, vi); Vh[i] = u.u;
    }
    int n4 = e_total >> 2;
    for (int i = gtid; i < n4; i += stride) {
        iv4 v = ld_nt_iv4(dst + 4 * i);
        atomicAdd(&h[((unsigned)v[0]) >> PBE_BSHIFT], 1u);
        atomicAdd(&h[((unsigned)v[1]) >> PBE_BSHIFT], 1u);
        atomicAdd(&h[((unsigned)v[2]) >> PBE_BSHIFT], 1u);
        atomicAdd(&h[((unsigned)v[3]) >> PBE_BSHIFT], 1u);
    }
    if (blockIdx.x == 0) {
        for (int t = (n4 << 2) + threadIdx.x; t < e_total; t += blockDim.x)
            atomicAdd(&h[((unsigned)dst[t]) >> PBE_BSHIFT], 1u);
    }
    __syncthreads();
    for (int b = threadIdx.x; b < PBE_NB; b += blockDim.x)
        if (h[b]) atomicAdd(&hist_g[b], h[b]);
}

// ---------------- prefix -> base, cursor -------------------------------------
__global__ void pbe_prefix(const unsigned* __restrict__ hist_g,
                           unsigned* __restrict__ base,
                           unsigned* __restrict__ cursor) {
    __shared__ unsigned tmp[PBE_NB];
    int t = threadIdx.x;
    unsigned mine = hist_g[t];
    tmp[t] = mine;
    __syncthreads();
    for (int o = 1; o < PBE_NB; o <<= 1) {
        unsigned u = (t >= o) ? tmp[t - o] : 0u;
        __syncthreads();
        tmp[t] += u;
        __syncthreads();
    }
    unsigned excl = tmp[t] - mine;
    base[t] = excl;
    cursor[t] = excl;
}

// ---------------- bin: LDS-staged bucket sort, 1 LDS atomic per edge ---------
// Scalar NT stream loads (best measured FETCH: vector streams evict Vh lines).
// LDS: hist 2K + lbase 2K + wsum 32 + staged 4 + recs 32K ~= 36.9 KB
// -> 4 blocks/CU.
__global__ void __launch_bounds__(PBE_NTB)
pbe_bin(const float2* __restrict__ Y,
        const int* __restrict__ src,
        const int* __restrict__ dst,
        const unsigned* __restrict__ Vh,
        ull* __restrict__ rec,
        unsigned* __restrict__ cursor,
        int e_total) {
    __shared__ unsigned hist[PBE_NB];     // phase1: counts; phase2+: delta
    __shared__ unsigned lbase[PBE_NB];    // phase2+: exclusive prefix (const)
    __shared__ unsigned wsum[8];
    __shared__ unsigned staged_sh;
    __shared__ ull recs[PBE_TILE];        // 32 KB (bkt in bits 44+)

    const int tile0 = blockIdx.x * PBE_TILE;
    const int tid = threadIdx.x;
    hist[tid] = 0;                        // PBE_NTB == PBE_NB == 512
    __syncthreads();

    // phase 1: dst loads + fused histogram/rank (1 LDS atomic per edge)
    int d[PBE_EPT];
    unsigned short r[PBE_EPT];
    #pragma unroll
    for (int k = 0; k < PBE_EPT; ++k) {
        int i = tile0 + k * PBE_NTB + tid;
        d[k] = (i < e_total) ? ld_nt_i(dst + i) : -1;
    }
    #pragma unroll
    for (int k = 0; k < PBE_EPT; ++k) {
        r[k] = 0;
        if (d[k] >= 0)
            r[k] = (unsigned short)atomicAdd(&hist[((unsigned)d[k]) >> PBE_BSHIFT], 1u);
    }
    __syncthreads();

    // phase 2: shfl wave-scan + cross-wave scan + exact global reservation.
    // After: lbase[b] = tile-local excl prefix (const afterwards),
    //        hist[b] = delta (global_base - local_base), staged_sh = count.
    {
        unsigned mine = hist[tid];
        unsigned v = mine;
        #pragma unroll
        for (int o = 1; o < 64; o <<= 1) {
            unsigned u = __shfl_up(v, o);
            if ((tid & 63) >= o) v += u;
        }
        if ((tid & 63) == 63) wsum[tid >> 6] = v;
        __syncthreads();
        if (tid == 0) {
            unsigned acc = 0;
            #pragma unroll
            for (int wv = 0; wv < 8; ++wv) {
                unsigned t = wsum[wv]; wsum[wv] = acc; acc += t;
            }
        }
        __syncthreads();
        unsigned incl = v + wsum[tid >> 6];
        unsigned excl = incl - mine;
        lbase[tid] = excl;
        if (tid == PBE_NB - 1) staged_sh = incl;
        unsigned g = mine ? atomicAdd(&cursor[tid], mine) : 0u;
        hist[tid] = g - excl;             // delta; per-thread slot, no hazard
    }
    __syncthreads();

    // phase 3: batched scalar loads + gathers -> LDS scatter at
    // lbase[b] + rank (no atomic).
    {
        int s[PBE_EPT]; unsigned uv[PBE_EPT]; float2 y[PBE_EPT];
        #pragma unroll
        for (int j = 0; j < PBE_EPT; ++j) {
            int i = tile0 + j * PBE_NTB + tid;
            s[j] = (d[j] >= 0) ? ld_nt_i(src + i) : 0;
        }
        #pragma unroll
        for (int j = 0; j < PBE_EPT; ++j) uv[j] = Vh[s[j]];  // random gathers
        #pragma unroll
        for (int j = 0; j < PBE_EPT; ++j) {
            int i = tile0 + j * PBE_NTB + tid;
            y[j] = (d[j] >= 0) ? ld_nt_f2(Y + i) : make_float2(0.f, 0.f);
        }
        #pragma unroll
        for (int j = 0; j < PBE_EPT; ++j) {
            if (d[j] < 0) continue;
            unsigned b = ((unsigned)d[j]) >> PBE_BSHIFT;
            unsigned pos = lbase[b] + r[j];
            H2U uvh; uvh.u = uv[j];
            float vr = __low2float(uvh.h), vi = __high2float(uvh.h);
            float mr = y[j].x * vr - y[j].y * vi;
            float mi = y[j].x * vi + y[j].y * vr;
            H2U um; um.h = __floats2half2_rn(mr, mi);
            recs[pos] = ((ull)b << 44)
                      | ((ull)(unsigned)(d[j] & (PBE_BSIZE - 1)) << 32)
                      | um.u;
        }
    }
    __syncthreads();

    // phase 4: coalesced copy-out; strip bucket bits. NT stores keep rec
    // lines out of L2 (preserves Vh residency).
    unsigned staged = staged_sh;
    for (unsigned j = tid; j < staged; j += PBE_NTB) {
        ull rr = recs[j];
        unsigned b = (unsigned)(rr >> 44);
        __builtin_nontemporal_store(rr & 0xFFFFFFFFFFFull, &rec[j + hist[b]]);
    }
}

// ---------------- per-bucket accumulate + fused residual reduce --------------
#define PBE_NTA 1024
__global__ void __launch_bounds__(PBE_NTA)
pbe_bucket_acc_red(const ull* __restrict__ rec,
                   const unsigned* __restrict__ base,
                   const unsigned* __restrict__ cursor, // post-bin end
                   const float* __restrict__ V,
                   const float* __restrict__ S,
                   float* __restrict__ sums, int n_nodes) {
    __shared__ int accR[PBE_BSIZE];
    __shared__ int accI[PBE_BSIZE];
    for (int j = threadIdx.x; j < PBE_BSIZE; j += PBE_NTA) { accR[j] = 0; accI[j] = 0; }
    __syncthreads();
    const int b = blockIdx.x;
    const unsigned lo = base[b], hi = cursor[b];
    for (unsigned t = lo + threadIdx.x; t < hi; t += PBE_NTA) {
        ull p = __builtin_nontemporal_load(rec + t);
        H2U um; um.u = (unsigned)p;
        unsigned dl = (unsigned)(p >> 32) & (PBE_BSIZE - 1);
        atomicAdd(&accR[dl], __float2int_rn(__low2float(um.h) * PBE_SCALE_LDS));
        atomicAdd(&accI[dl], __float2int_rn(__high2float(um.h) * PBE_SCALE_LDS));
    }
    __syncthreads();
    const int node0 = b << PBE_BSHIFT;
    float a0 = 0.f, a1 = 0.f, a2 = 0.f;
    for (int j = threadIdx.x; j < PBE_BSIZE; j += PBE_NTA) {
        int n = node0 + j;
        if (n < n_nodes) {
            float2 v  = reinterpret_cast<const float2*>(V)[n];
            float2 sb = reinterpret_cast<const float2*>(S)[n];
            float cr = accR[j] * PBE_INV_SCALE_LDS;
            float ci = accI[j] * PBE_INV_SCALE_LDS;
            float rr = sb.x - (v.x * cr + v.y * ci);
            float ri = sb.y - (v.y * cr - v.x * ci);
            a0 += sqrtf(rr * rr + ri * ri);
            a1 += fabsf(rr);
            a2 += fabsf(ri);
        }
    }
    #pragma unroll
    for (int off = 32; off > 0; off >>= 1) {
        a0 += __shfl_down(a0, off);
        a1 += __shfl_down(a1, off);
        a2 += __shfl_down(a2, off);
    }
    __shared__ float sm[3][PBE_NTA / 64];
    int wid  = threadIdx.x >> 6;
    int lane = threadIdx.x & 63;
    if (lane == 0) { sm[0][wid] = a0; sm[1][wid] = a1; sm[2][wid] = a2; }
    __syncthreads();
    if (threadIdx.x == 0) {
        float t0 = 0.f, t1 = 0.f, t2 = 0.f;
        #pragma unroll
        for (int wv = 0; wv < PBE_NTA / 64; ++wv) {
            t0 += sm[0][wv]; t1 += sm[1][wv]; t2 += sm[2][wv];
        }
        atomicAdd(&sums[0], t0);
        atomicAdd(&sums[1], t1);
        atomicAdd(&sums[2], t2);
    }
}

// ---------------- fallback path ----------------------------------------------
__global__ void pbe_node_prep(const float* __restrict__ pred,
                              const float* __restrict__ target,
                              const int* __restrict__ mask,
                              float* __restrict__ V,
                              float* __restrict__ S,
                              int n) {
    int i = blockIdx.x * blockDim.x + threadIdx.x;
    int stride = gridDim.x * blockDim.x;
    for (; i < n; i += stride) {
        int b = 6 * i;
        float2 p0 = ld_nt_f2((const float2*)(pred + b));
        float2 p1 = ld_nt_f2((const float2*)(pred + b + 2));
        float2 p2 = ld_nt_f2((const float2*)(pred + b + 4));
        float2 t0 = ld_nt_f2((const float2*)(target + b));
        float2 t1 = ld_nt_f2((const float2*)(target + b + 2));
        float2 t2 = ld_nt_f2((const float2*)(target + b + 4));
        int2 m0 = ld_nt_i2(mask + b);
        int2 m1 = ld_nt_i2(mask + b + 2);
        int2 m2 = ld_nt_i2(mask + b + 4);
        float pd = m0.x ? p0.x : t0.x;
        float qd = m0.y ? p0.y : t0.y;
        float pg = m1.x ? p1.x : t1.x;
        float qg = m1.y ? p1.y : t1.y;
        float vm = m2.x ? p2.x : t2.x;
        float va = m2.y ? p2.y : t2.y;
        float sn, cs;
        sincosf(va, &sn, &cs);
        V[2 * i + 0] = vm * cs;
        V[2 * i + 1] = vm * sn;
        S[2 * i + 0] = pg - pd;
        S[2 * i + 1] = qg - qd;
    }
}

__device__ __forceinline__ void pbe_edge_one(float2 gb, int s, int d,
                                             const float2* __restrict__ V,
                                             ull* __restrict__ Iq) {
    float2 v = V[s];
    float mr = gb.x * v.x - gb.y * v.y;
    float mi = gb.x * v.y + gb.y * v.x;
    int qr = __float2int_rn(mr * PBE_SCALE64);
    int qi = __float2int_rn(mi * PBE_SCALE64);
    ull pack = ((ull)(unsigned)qr << 32) + (ull)(long long)qi;
    atomicAdd(&Iq[d], pack);
}

__global__ void __launch_bounds__(PBE_NT)
pbe_edge_scatter(const float2* __restrict__ edge_attr,
                 const int* __restrict__ src,
                 const int* __restrict__ dst,
                 const float2* __restrict__ V,
                 ull* __restrict__ Iq,
                 int e_total) {
    int i = blockIdx.x * blockDim.x + threadIdx.x;
    const int stride = gridDim.x * blockDim.x;
    for (; i < e_total; i += stride) {
        float2 g = ld_nt_f2(edge_attr + i);
        pbe_edge_one(g, ld_nt_i(src + i), ld_nt_i(dst + i), V, Iq);
    }
}

__global__ void pbe_unpack_iq(ull* __restrict__ Iq, float* __restrict__ I, int n) {
    int i = blockIdx.x * blockDim.x + threadIdx.x;
    int stride = gridDim.x * blockDim.x;
    for (; i < n; i += stride) {
        long long q = (long long)Iq[i];
        int lo = (int)(unsigned)(q & 0xFFFFFFFFll);
        int hi = (int)((q - (long long)lo) >> 32);
        I[2 * i + 0] = hi * PBE_INV_SCALE64;
        I[2 * i + 1] = lo * PBE_INV_SCALE64;
    }
}

__global__ void pbe_reduce(const float* __restrict__ V,
                           const float* __restrict__ S,
                           const float* __restrict__ I,
                           float* __restrict__ sums, int n) {
    float a0 = 0.f, a1 = 0.f, a2 = 0.f;
    int i = blockIdx.x * blockDim.x + threadIdx.x;
    int stride = gridDim.x * blockDim.x;
    for (; i < n; i += stride) {
        float2 v  = reinterpret_cast<const float2*>(V)[i];
        float2 sb = reinterpret_cast<const float2*>(S)[i];
        float2 cc = reinterpret_cast<const float2*>(I)[i];
        float rr = sb.x - (v.x * cc.x + v.y * cc.y);
        float ri = sb.y - (v.y * cc.x - v.x * cc.y);
        a0 += sqrtf(rr * rr + ri * ri);
        a1 += fabsf(rr);
        a2 += fabsf(ri);
    }
    #pragma unroll
    for (int off = 32; off > 0; off >>= 1) {
        a0 += __shfl_down(a0, off);
        a1 += __shfl_down(a1, off);
        a2 += __shfl_down(a2, off);
    }
    __shared__ float sm[3][PBE_NT / 64];
    int wid  = threadIdx.x >> 6;
    int lane = threadIdx.x & 63;
    if (lane == 0) { sm[0][wid] = a0; sm[1][wid] = a1; sm[2][wid] = a2; }
    __syncthreads();
    if (threadIdx.x == 0) {
        float t0 = 0.f, t1 = 0.f, t2 = 0.f;
        #pragma unroll
        for (int w = 0; w < PBE_NT / 64; ++w) {
            t0 += sm[0][w]; t1 += sm[1][w]; t2 += sm[2][w];
        }
        atomicAdd(&sums[0], t0);
        atomicAdd(&sums[1], t1);
        atomicAdd(&sums[2], t2);
    }
}

__global__ void pbe_finalize(const float* __restrict__ sums,
                             float* __restrict__ out, float inv_n) {
    int t = threadIdx.x;
    if (t < 3) out[t] = sums[t] * inv_n;
}

static inline size_t align256(size_t x) { return (x + 255) & ~(size_t)255; }

extern "C" void kernel_launch(void* const* d_in, const int* in_sizes, int n_in,
                              void* d_out, int out_size, void* d_ws, size_t ws_size,
                              hipStream_t stream) {
    const float* pred      = (const float*)d_in[0];
    const float* target    = (const float*)d_in[1];
    const float* edge_attr = (const float*)d_in[2];
    const int*   edge_idx  = (const int*)d_in[3]; // [2, E] int32
    const int*   mask      = (const int*)d_in[4]; // bool -> int32

    const int n_nodes = in_sizes[0] / 6;
    const int n_edges = in_sizes[2] / 2;
    const int* src = edge_idx;
    const int* dst = edge_idx + n_edges;

    const int NBa     = (n_nodes + PBE_BSIZE - 1) / PBE_BSIZE;  // active buckets
    const int n_tiles = (n_edges + PBE_TILE - 1) / PBE_TILE;

    char* w = (char*)d_ws;
    size_t oV    = 0;
    size_t oS    = align256(oV + (size_t)2 * n_nodes * 4);
    size_t oVh   = align256(oS + (size_t)2 * n_nodes * 4);
    size_t oRec  = align256(oVh + (size_t)n_nodes * 4);
    size_t oHist = align256(oRec + (size_t)n_edges * 8);   // exact capacity
    size_t oBase = align256(oHist + PBE_NB * 4);
    size_t oCur  = align256(oBase + PBE_NB * 4);
    size_t oSums = align256(oCur + PBE_NB * 4);
    size_t need  = oSums + 3 * 4;

    float*    V      = (float*)(w + oV);
    float*    S      = (float*)(w + oS);
    unsigned* Vh     = (unsigned*)(w + oVh);
    ull*      rec    = (ull*)(w + oRec);
    unsigned* hist_g = (unsigned*)(w + oHist);
    unsigned* base   = (unsigned*)(w + oBase);
    unsigned* cursor = (unsigned*)(w + oCur);
    float*    sums   = (float*)(w + oSums);

    const bool fast = (ws_size >= need) && (NBa <= PBE_NB);

    const int T = PBE_NT;
    int grid_nodes = (n_nodes + T - 1) / T;
    if (grid_nodes > 2048) grid_nodes = 2048;

    if (fast) {
        hipMemsetAsync(hist_g, 0, PBE_NB * sizeof(unsigned), stream);
        hipMemsetAsync(sums, 0, 3 * sizeof(float), stream);

        pbe_prep_hist<<<2048, T, 0, stream>>>(pred, target, mask, V, S, Vh,
                                              n_nodes, dst, hist_g, n_edges);
        pbe_prefix<<<1, PBE_NB, 0, stream>>>(hist_g, base, cursor);
        pbe_bin<<<n_tiles, PBE_NTB, 0, stream>>>((const float2*)edge_attr, src, dst,
                                                 Vh, rec, cursor, n_edges);
        pbe_bucket_acc_red<<<NBa, PBE_NTA, 0, stream>>>(rec, base, cursor, V, S,
                                                        sums, n_nodes);
        pbe_finalize<<<1, 64, 0, stream>>>(sums, (float*)d_out, 1.0f / (float)n_nodes);
    } else {
        // fallback: packed 64-bit fixed-point atomics (round-3 scheme)
        ull* Iq = (ull*)(w + oRec);
        float* sums_fb = (float*)(w + oVh);
        hipMemsetAsync(Iq, 0, (size_t)n_nodes * 8, stream);
        hipMemsetAsync(sums_fb, 0, 3 * sizeof(float), stream);
        int grid_edges = (n_edges + T - 1) / T;
        if (grid_edges > 8192) grid_edges = 8192;
        pbe_node_prep<<<grid_nodes, T, 0, stream>>>(pred, target, mask, V, S, n_nodes);
        pbe_edge_scatter<<<grid_edges, T, 0, stream>>>(
            (const float2*)edge_attr, src, dst, (const float2*)V, Iq, n_edges);
        pbe_unpack_iq<<<grid_nodes, T, 0, stream>>>(Iq, (float*)Iq, n_nodes);
        pbe_reduce<<<grid_nodes, T, 0, stream>>>(V, S, (float*)Iq, sums_fb, n_nodes);
        pbe_finalize<<<1, 64, 0, stream>>>(sums_fb, (float*)d_out, 1.0f / (float)n_nodes);
    }
}